// Round 7
// baseline (936.727 us; speedup 1.0000x reference)
//
#include <hip/hip_runtime.h>
#include <hip/hip_fp16.h>

// Hankel MPS, round 7: plain-launch pipeline, btile-256 chain with
// plane-fed B-frags; per-step split kernel (sum partials -> bf16 hi/lo planes).
//
// prep:  W1,W2 -> fp16 frag-ordered; H_mid -> frag-ordered bf16 hi/lo (coalesced)
// enc:   fp16 MFMA 2-layer MLP (round-4, unchanged)
// init:  v0[p][b] = sum_e enc0 * Hf  (fp32)
// split: planes[b][p] (hi,lo u16) = bf16-split of sum of nIn partials
// chain x10: grid 256 = 32 btile(256 b) x 8 eg(16 e), 512 thr (8 waves:
//   mf=wv>>2, bh=wv&3). B-frags direct from planes (16B/lane); A-frags
//   direct global->VGPR (frag-ordered H, L2-hot); partial out [g][r][b].
// reduce_t + final: round-5, unchanged.
//
// ws: encH 25.17M | HmH 10.49M | HmL 10.49M | w1f 64K | w2f 128K |
//     v0/vT 2M | vHi 1M | vLo 1M | pA 16.78M  -> 67.3 MB (round5 proved >=82)

#define B_ALL 8192

typedef short bfrag __attribute__((ext_vector_type(8)));      // 8 bf16
typedef _Float16 hfrag __attribute__((ext_vector_type(8)));   // 8 fp16
typedef float ffrag __attribute__((ext_vector_type(16)));     // 32x32 C/D

#define O_ENC   0ULL
#define O_HMH   25165824ULL
#define O_HML   35651584ULL
#define O_W1F   46137344ULL
#define O_W2F   46202880ULL
#define O_V0    46333952ULL     // 2 MB; aliased as vT at the end
#define O_VHI   48431104ULL     // 1 MB
#define O_VLO   49479680ULL     // 1 MB
#define O_PA    50528256ULL     // 16.78 MB

__device__ __forceinline__ unsigned short bf16_rne(float f) {
    unsigned int u = __builtin_bit_cast(unsigned int, f);
    unsigned int r = (u + 0x7fffu + ((u >> 16) & 1u)) >> 16;
    return (unsigned short)r;
}
__device__ __forceinline__ float bf16_f32(unsigned short h) {
    unsigned int u = ((unsigned int)h) << 16;
    return __builtin_bit_cast(float, u);
}

// ---------------- prep: coalesced frag-reorder (round-6 logic) ----------------
__global__ __launch_bounds__(256)
void prep_kernel(const float* __restrict__ W1, const float* __restrict__ W2,
                 const float* __restrict__ Hm,
                 __half* __restrict__ w1f, __half* __restrict__ w2f,
                 unsigned short* __restrict__ Hh, unsigned short* __restrict__ Hl)
{
    const int tid = threadIdx.x;
    if (blockIdx.x < 2560) {
        const int wv = tid >> 6;
        const int wtask = blockIdx.x * 4 + wv;      // 10240 = (t,e,mf,s)
        const int t = wtask >> 10;
        const int rem = wtask & 1023;
        const int e = rem >> 3;
        const int mf = (rem >> 2) & 1, s = rem & 3;
        const int lane = tid & 63;
        const int half = lane >> 5, l32 = lane & 31;
        const int r = mf * 32 + l32;
        unsigned short hi8[8], lo8[8];
        #pragma unroll
        for (int j = 0; j < 8; ++j) {
            const int p = s * 16 + half * 8 + j;
            const float val = Hm[(((size_t)t * 64 + p) * 128 + e) * 64 + r];
            const unsigned short hi = bf16_rne(val);
            hi8[j] = hi;
            lo8[j] = bf16_rne(val - bf16_f32(hi));
        }
        const size_t base = ((size_t)t * 128 + e) * 4096
                          + (size_t)((((mf * 4 + s) * 2 + half) * 32 + l32) * 8);
        *(uint4*)(Hh + base) = *(const uint4*)hi8;
        *(uint4*)(Hl + base) = *(const uint4*)lo8;
    } else {
        const int tix = (blockIdx.x - 2560) * 256 + tid;   // 8192 threads
        for (int w = tix; w < 32768; w += 8192) {
            const int jn = w >> 11, ks = (w >> 9) & 3, hf2 = (w >> 8) & 1;
            const int jl = (w >> 3) & 31, jj = w & 7;
            w1f[w] = __float2half(W1[(jn * 32 + jl) * 64 + ks * 16 + hf2 * 8 + jj]);
        }
        for (int w = tix; w < 65536; w += 8192) {
            const int en = w >> 14, ks2g = (w >> 9) & 31, hf2 = (w >> 8) & 1;
            const int el = (w >> 3) & 31, jj = w & 7;
            w2f[w] = __float2half(W2[(en * 32 + el) * 512 + ks2g * 16 + hf2 * 8 + jj]);
        }
    }
}

// ---------------- encoder (round-4/5, unchanged) ----------------
__global__ __launch_bounds__(256)
void enc_kernel(const float* __restrict__ x,
                const float* __restrict__ b1, const float* __restrict__ b2,
                const __half* __restrict__ w1f, const __half* __restrict__ w2f,
                __half* __restrict__ encH)
{
    __shared__ __align__(16) unsigned char smem[17408];
    float* x_s  = (float*)smem;
    __half* h_s = (__half*)smem;

    const int tid   = threadIdx.x;
    const int wv    = tid >> 6;
    const int lane  = tid & 63;
    const int l32   = lane & 31;
    const int half  = lane >> 5;
    const int msub  = wv >> 1;
    const int nhalf = wv & 1;
    const int m0    = blockIdx.x * 64;

    #pragma unroll
    for (int i = 0; i < 4; ++i) {
        const int f4 = i * 256 + tid;
        const int r = f4 >> 4, c4 = (f4 & 15) * 4;
        *(float4*)&x_s[r * 68 + c4] =
            *(const float4*)&x[(long long)(m0 + r) * 64 + c4];
    }
    __syncthreads();

    hfrag xa[4];
    #pragma unroll
    for (int ks = 0; ks < 4; ++ks) {
        const float* src = &x_s[(msub * 32 + l32) * 68 + ks * 16 + half * 8];
        const float4 a = *(const float4*)src;
        const float4 b = *(const float4*)(src + 4);
        hfrag v;
        v[0] = (_Float16)a.x; v[1] = (_Float16)a.y;
        v[2] = (_Float16)a.z; v[3] = (_Float16)a.w;
        v[4] = (_Float16)b.x; v[5] = (_Float16)b.y;
        v[6] = (_Float16)b.z; v[7] = (_Float16)b.w;
        xa[ks] = v;
    }
    __syncthreads();

    ffrag c2[2];
    c2[0] = 0.0f; c2[1] = 0.0f;

    for (int chunk = 0; chunk < 4; ++chunk) {
        ffrag c1[2];
        float b1j[2];
        #pragma unroll
        for (int nf = 0; nf < 2; ++nf) {
            const int jn = chunk * 4 + nhalf * 2 + nf;
            b1j[nf] = b1[jn * 32 + l32];
            ffrag acc = 0.0f;
            #pragma unroll
            for (int ks = 0; ks < 4; ++ks) {
                const hfrag bh = *(const hfrag*)(w1f + (jn * 4 + ks) * 512
                                                 + half * 256 + l32 * 8);
                acc = __builtin_amdgcn_mfma_f32_32x32x16_f16(xa[ks], bh, acc, 0, 0, 0);
            }
            c1[nf] = acc;
        }
        __syncthreads();
        #pragma unroll
        for (int nf = 0; nf < 2; ++nf) {
            #pragma unroll
            for (int i2 = 0; i2 < 16; ++i2) {
                const int m_row = (i2 & 3) + 8 * (i2 >> 2) + 4 * half;
                const float v = fmaxf(c1[nf][i2] + b1j[nf], 0.0f);
                h_s[(msub * 32 + m_row) * 136 + nhalf * 64 + nf * 32 + l32] =
                    __float2half(v);
            }
        }
        __syncthreads();
        #pragma unroll
        for (int ks2 = 0; ks2 < 8; ++ks2) {
            const hfrag a = *(const hfrag*)&h_s[(msub * 32 + l32) * 136
                                                + ks2 * 16 + half * 8];
            const int ks2g = chunk * 8 + ks2;
            #pragma unroll
            for (int ef = 0; ef < 2; ++ef) {
                const int en = nhalf * 2 + ef;
                const hfrag b = *(const hfrag*)(w2f + (en * 32 + ks2g) * 512
                                                + half * 256 + l32 * 8);
                c2[ef] = __builtin_amdgcn_mfma_f32_32x32x16_f16(a, b, c2[ef], 0, 0, 0);
            }
        }
    }

    #pragma unroll
    for (int ef = 0; ef < 2; ++ef) {
        const int e = nhalf * 64 + ef * 32 + l32;
        const float b2e = b2[e];
        #pragma unroll
        for (int i2 = 0; i2 < 16; ++i2) {
            const int m_row = (i2 & 3) + 8 * (i2 >> 2) + 4 * half;
            const int m_g = m0 + msub * 32 + m_row;
            encH[(long long)m_g * 128 + e] =
                __float2half(fmaxf(c2[ef][i2] + b2e, 0.0f));
        }
    }
}

// ---------------- init: v0[p][b] (round-5, unchanged) ----------------
__global__ __launch_bounds__(256, 2)
void init_kernel(const __half* __restrict__ encH, const float* __restrict__ Hf,
                 float* __restrict__ vOut)   // [64][8192]
{
    __shared__ float enc_s[64 * 129];
    const int tid = threadIdx.x;
    const int b0 = blockIdx.x * 64;     // grid 128
    {
        const int b = tid >> 2, ec = (tid & 3) * 32;
        const __half* er = encH + ((size_t)(b0 + b) * 12 + 0) * 128 + ec;
        #pragma unroll
        for (int q = 0; q < 4; ++q) {
            uint4 u = *(const uint4*)(er + q * 8);
            const __half* hp = (const __half*)&u;
            #pragma unroll
            for (int j = 0; j < 8; ++j)
                enc_s[b * 129 + ec + q * 8 + j] = __half2float(hp[j]);
        }
    }
    __syncthreads();
    const int wv = tid >> 6, lane = tid & 63;
    const int b = b0 + lane;
    for (int pc = 0; pc < 16; pc += 4) {
        const int p = wv * 16 + pc;
        float a0 = 0, a1 = 0, a2 = 0, a3 = 0;
        for (int e = 0; e < 128; ++e) {
            const float ev = enc_s[lane * 129 + e];
            const float4 h = *(const float4*)&Hf[e * 64 + p];
            a0 += ev * h.x; a1 += ev * h.y; a2 += ev * h.z; a3 += ev * h.w;
        }
        vOut[(size_t)(p + 0) * B_ALL + b] = a0;
        vOut[(size_t)(p + 1) * B_ALL + b] = a1;
        vOut[(size_t)(p + 2) * B_ALL + b] = a2;
        vOut[(size_t)(p + 3) * B_ALL + b] = a3;
    }
}

// ---------------- split: sum nIn partials -> bf16 hi/lo planes [b][p] ----------------
__global__ __launch_bounds__(256)
void split_kernel(const float* __restrict__ vIn, int nIn,
                  unsigned short* __restrict__ vHi,
                  unsigned short* __restrict__ vLo)
{
    __shared__ float vsum[64 * 133];
    const int tid = threadIdx.x;
    const int b0 = blockIdx.x * 128;   // grid 64
    #pragma unroll
    for (int k = 0; k < 8; ++k) {
        const int p  = (tid >> 5) + k * 8;
        const int bl = (tid & 31) * 4;
        float4 s4 = {0.f, 0.f, 0.f, 0.f};
        for (int g = 0; g < nIn; ++g) {
            const float4 u = *(const float4*)&vIn[(size_t)g * 524288
                                                  + (size_t)p * B_ALL + b0 + bl];
            s4.x += u.x; s4.y += u.y; s4.z += u.z; s4.w += u.w;
        }
        *(float4*)&vsum[p * 133 + bl] = s4;
    }
    __syncthreads();
    const int bl = tid >> 1, seg = tid & 1;
    const int p0 = seg * 32;
    unsigned short hi[32], lo[32];
    #pragma unroll
    for (int p = 0; p < 32; ++p) {
        const float f = vsum[(p0 + p) * 133 + bl];
        const unsigned short h = bf16_rne(f);
        hi[p] = h;
        lo[p] = bf16_rne(f - bf16_f32(h));
    }
    const size_t a = (size_t)(b0 + bl) * 64 + p0;
    #pragma unroll
    for (int q = 0; q < 4; ++q) {
        *(uint4*)(vHi + a + q * 8) = *(const uint4*)(hi + q * 8);
        *(uint4*)(vLo + a + q * 8) = *(const uint4*)(lo + q * 8);
    }
}

// ---------------- chain step: btile 256, plane-fed B-frags ----------------
__global__ __launch_bounds__(512, 4)
void chain_step(const unsigned short* __restrict__ Hth,  // this t hi [128e][4096]
                const unsigned short* __restrict__ Htl,
                const __half* __restrict__ encH,
                const unsigned short* __restrict__ vHi,  // [b][64]
                const unsigned short* __restrict__ vLo,
                float* __restrict__ pOut,                // [8][64][8192]
                int t)
{
    __shared__ float enc_s[16 * 260];
    const int tid = threadIdx.x;
    const int m = blockIdx.x & 31;     // 32 btiles
    const int g = blockIdx.x >> 5;     // 8 e-groups
    const int b0 = m * 256;
    const int e0 = g * 16;

    // stage enc [16 e][256 b]
    {
        const int bl = tid >> 1, eh = tid & 1;
        const __half* er = encH + ((size_t)((b0 + bl) * 12 + t)) * 128 + e0 + eh * 8;
        uint4 u = *(const uint4*)er;
        const __half* hp = (const __half*)&u;
        #pragma unroll
        for (int k = 0; k < 8; ++k)
            enc_s[(eh * 8 + k) * 260 + bl] = __half2float(hp[k]);
    }

    const int wv = tid >> 6, lane = tid & 63;
    const int l32 = lane & 31, half = lane >> 5;
    const int mf = wv >> 2, bh = wv & 3;

    // B-frags direct from planes (16 B/lane dwordx4)
    bfrag vbh_[2][4], vbl_[2][4];
    #pragma unroll
    for (int nf = 0; nf < 2; ++nf) {
        const int b = b0 + bh * 64 + nf * 32 + l32;
        #pragma unroll
        for (int s = 0; s < 4; ++s) {
            const size_t a = (size_t)b * 64 + s * 16 + half * 8;
            vbh_[nf][s] = *(const bfrag*)(vHi + a);
            vbl_[nf][s] = *(const bfrag*)(vLo + a);
        }
    }
    __syncthreads();

    ffrag z = 0.0f;
    ffrag vn0 = 0.0f, vn1 = 0.0f;

    #pragma unroll 2
    for (int e = 0; e < 16; ++e) {
        const float ev0 = enc_s[e * 260 + bh * 64 + l32];
        const float ev1 = enc_s[e * 260 + bh * 64 + 32 + l32];
        const unsigned short* hb = Hth + (size_t)(e0 + e) * 4096;
        const unsigned short* lb = Htl + (size_t)(e0 + e) * 4096;
        ffrag wa = z, wb = z;
        #pragma unroll
        for (int s = 0; s < 4; ++s) {
            const int fo = (((mf * 4 + s) * 2 + half) * 32 + l32) * 8;
            const bfrag ah = *(const bfrag*)(hb + fo);
            const bfrag al = *(const bfrag*)(lb + fo);
            wa = __builtin_amdgcn_mfma_f32_32x32x16_bf16(ah, vbh_[0][s], wa, 0, 0, 0);
            wa = __builtin_amdgcn_mfma_f32_32x32x16_bf16(ah, vbl_[0][s], wa, 0, 0, 0);
            wa = __builtin_amdgcn_mfma_f32_32x32x16_bf16(al, vbh_[0][s], wa, 0, 0, 0);
            wb = __builtin_amdgcn_mfma_f32_32x32x16_bf16(ah, vbh_[1][s], wb, 0, 0, 0);
            wb = __builtin_amdgcn_mfma_f32_32x32x16_bf16(ah, vbl_[1][s], wb, 0, 0, 0);
            wb = __builtin_amdgcn_mfma_f32_32x32x16_bf16(al, vbh_[1][s], wb, 0, 0, 0);
        }
        vn0 += wa * ev0;
        vn1 += wb * ev1;
    }

    #pragma unroll
    for (int nf = 0; nf < 2; ++nf) {
        const ffrag vv = nf ? vn1 : vn0;
        const int b = b0 + bh * 64 + nf * 32 + l32;
        #pragma unroll
        for (int i = 0; i < 16; ++i) {
            const int r = mf * 32 + (i & 3) + 8 * (i >> 2) + 4 * half;
            pOut[(size_t)g * 524288 + (size_t)r * B_ALL + b] = vv[i];
        }
    }
}

// ---------------- reduce + transpose (round-5, unchanged) ----------------
__global__ __launch_bounds__(256)
void reduce_t_kernel(const float* __restrict__ vIn, int nIn,
                     float* __restrict__ vT)   // [8192][64]
{
    __shared__ float vt[64][68];
    const int tid = threadIdx.x;
    const int b0 = blockIdx.x * 64;   // grid 128
    #pragma unroll
    for (int k = 0; k < 8; ++k) {
        const int p  = (tid >> 5) + k * 8;
        const int bl = (tid & 31) * 2;
        float2 s = {0.f, 0.f};
        for (int g = 0; g < nIn; ++g) {
            const float2 u = *(const float2*)&vIn[(size_t)g * 524288
                                                  + (size_t)p * B_ALL + b0 + bl];
            s.x += u.x; s.y += u.y;
        }
        vt[bl][p] = s.x;
        vt[bl + 1][p] = s.y;
    }
    __syncthreads();
    const int b = tid >> 2, c = (tid & 3) * 16;
    float4* dst = (float4*)&vT[(size_t)(b0 + b) * 64 + c];
    #pragma unroll
    for (int q = 0; q < 4; ++q)
        dst[q] = *(float4*)&vt[b][c + q * 4];
}

// ---------------- final (round-5, unchanged) ----------------
__global__ __launch_bounds__(64)
void final_kernel(const __half* __restrict__ encH, const float* __restrict__ HL,
                  const float* __restrict__ vT, float* __restrict__ out)
{
    __shared__ float hl_s[64 * 129];
    const int tid = threadIdx.x;
    const int b0 = blockIdx.x * 16;
    for (int i = 0; i < 128; ++i) {
        const int idx = i * 64 + tid;
        hl_s[(idx >> 7) * 129 + (idx & 127)] = HL[idx];
    }
    __syncthreads();
    const int p = tid;
    for (int bs = 0; bs < 16; ++bs) {
        const int b = b0 + bs;
        const __half* er = encH + (size_t)(b * 12 + 11) * 128;
        float L = 0.0f;
        #pragma unroll 16
        for (int e = 0; e < 128; ++e)
            L += __half2float(er[e]) * hl_s[p * 129 + e];
        float pre = vT[(size_t)b * 64 + p] * L;
        #pragma unroll
        for (int off = 32; off > 0; off >>= 1)
            pre += __shfl_down(pre, off);
        if (tid == 0) out[b] = pre;
    }
}

extern "C" void kernel_launch(void* const* d_in, const int* in_sizes, int n_in,
                              void* d_out, int out_size, void* d_ws, size_t ws_size,
                              hipStream_t stream) {
    const float* x  = (const float*)d_in[0];
    const float* W1 = (const float*)d_in[1];
    const float* b1 = (const float*)d_in[2];
    const float* W2 = (const float*)d_in[3];
    const float* b2 = (const float*)d_in[4];
    const float* Hf = (const float*)d_in[5];
    const float* Hm = (const float*)d_in[6];
    const float* HL = (const float*)d_in[7];
    float* out = (float*)d_out;
    (void)in_sizes; (void)n_in; (void)out_size; (void)ws_size;

    char* ws = (char*)d_ws;
    __half* encH        = (__half*)(ws + O_ENC);
    unsigned short* HmH = (unsigned short*)(ws + O_HMH);
    unsigned short* HmL = (unsigned short*)(ws + O_HML);
    __half* w1f         = (__half*)(ws + O_W1F);
    __half* w2f         = (__half*)(ws + O_W2F);
    float* v0           = (float*)(ws + O_V0);
    float* vT           = (float*)(ws + O_V0);   // alias: v0 dead before vT
    unsigned short* vHi = (unsigned short*)(ws + O_VHI);
    unsigned short* vLo = (unsigned short*)(ws + O_VLO);
    float* pA           = (float*)(ws + O_PA);

    prep_kernel<<<dim3(2592), dim3(256), 0, stream>>>(W1, W2, Hm, w1f, w2f, HmH, HmL);
    enc_kernel<<<dim3(1536), dim3(256), 0, stream>>>(x, b1, b2, w1f, w2f, encH);
    init_kernel<<<dim3(128), dim3(256), 0, stream>>>(encH, Hf, v0);
    split_kernel<<<dim3(64), dim3(256), 0, stream>>>(v0, 1, vHi, vLo);

    for (int t = 1; t <= 10; ++t) {
        chain_step<<<dim3(256), dim3(512), 0, stream>>>(
            HmH + (size_t)(t - 1) * 524288, HmL + (size_t)(t - 1) * 524288,
            encH, vHi, vLo, pA, t);
        if (t < 10)
            split_kernel<<<dim3(64), dim3(256), 0, stream>>>(pA, 8, vHi, vLo);
    }
    reduce_t_kernel<<<dim3(128), dim3(256), 0, stream>>>(pA, 8, vT);
    final_kernel<<<dim3(512), dim3(64), 0, stream>>>(encH, HL, vT, out);
}

// Round 9
// 683.722 us; speedup vs baseline: 1.3700x; 1.3700x over previous
//
#include <hip/hip_runtime.h>
#include <hip/hip_fp16.h>

// Hankel MPS, round 9: round-8 structure with split_kernel OOB/race fix
// (frag-unit loop k<4, 1024 units/block — bg_l strictly 0..3).
//
// prep:  W1,W2 -> fp16 frag-ordered; H_mid -> frag-ordered bf16 hi/lo
// enc:   fp16 MFMA 2-layer MLP
// init:  v0[p][b] (fp32)
// split: sum nIn partials -> bf16 hi/lo planes in MFMA FRAG ORDER
// chain x10: grid 512 = 64 btile(128b) x 8 eg(16e), 256 thr, lb(256,2).
//   B-frags: 16 coalesced dwordx4 from frag-planes, pinned in VGPRs via asm.
//   A-frags: global->VGPR per e (unroll 4). Partial out [g][r][b].
// reduce_t + final: unchanged.
//
// ws: encH 25.17M | HmH 10.49M | HmL 10.49M | w1f 64K | w2f 128K |
//     v0/vT 2M | vHi 1M | vLo 1M | pA 16.78M  -> 67.3 MB

#define B_ALL 8192

typedef short bfrag __attribute__((ext_vector_type(8)));      // 8 bf16
typedef _Float16 hfrag __attribute__((ext_vector_type(8)));   // 8 fp16
typedef float ffrag __attribute__((ext_vector_type(16)));     // 32x32 C/D
typedef int v4i __attribute__((ext_vector_type(4)));

#define O_ENC   0ULL
#define O_HMH   25165824ULL
#define O_HML   35651584ULL
#define O_W1F   46137344ULL
#define O_W2F   46202880ULL
#define O_V0    46333952ULL
#define O_VHI   48431104ULL
#define O_VLO   49479680ULL
#define O_PA    50528256ULL

__device__ __forceinline__ unsigned short bf16_rne(float f) {
    unsigned int u = __builtin_bit_cast(unsigned int, f);
    unsigned int r = (u + 0x7fffu + ((u >> 16) & 1u)) >> 16;
    return (unsigned short)r;
}
__device__ __forceinline__ float bf16_f32(unsigned short h) {
    unsigned int u = ((unsigned int)h) << 16;
    return __builtin_bit_cast(float, u);
}

// ---------------- prep (unchanged) ----------------
__global__ __launch_bounds__(256)
void prep_kernel(const float* __restrict__ W1, const float* __restrict__ W2,
                 const float* __restrict__ Hm,
                 __half* __restrict__ w1f, __half* __restrict__ w2f,
                 unsigned short* __restrict__ Hh, unsigned short* __restrict__ Hl)
{
    const int tid = threadIdx.x;
    if (blockIdx.x < 2560) {
        const int wv = tid >> 6;
        const int wtask = blockIdx.x * 4 + wv;      // 10240 = (t,e,mf,s)
        const int t = wtask >> 10;
        const int rem = wtask & 1023;
        const int e = rem >> 3;
        const int mf = (rem >> 2) & 1, s = rem & 3;
        const int lane = tid & 63;
        const int half = lane >> 5, l32 = lane & 31;
        const int r = mf * 32 + l32;
        unsigned short hi8[8], lo8[8];
        #pragma unroll
        for (int j = 0; j < 8; ++j) {
            const int p = s * 16 + half * 8 + j;
            const float val = Hm[(((size_t)t * 64 + p) * 128 + e) * 64 + r];
            const unsigned short hi = bf16_rne(val);
            hi8[j] = hi;
            lo8[j] = bf16_rne(val - bf16_f32(hi));
        }
        const size_t base = ((size_t)t * 128 + e) * 4096
                          + (size_t)((((mf * 4 + s) * 2 + half) * 32 + l32) * 8);
        *(uint4*)(Hh + base) = *(const uint4*)hi8;
        *(uint4*)(Hl + base) = *(const uint4*)lo8;
    } else {
        const int tix = (blockIdx.x - 2560) * 256 + tid;   // 8192 threads
        for (int w = tix; w < 32768; w += 8192) {
            const int jn = w >> 11, ks = (w >> 9) & 3, hf2 = (w >> 8) & 1;
            const int jl = (w >> 3) & 31, jj = w & 7;
            w1f[w] = __float2half(W1[(jn * 32 + jl) * 64 + ks * 16 + hf2 * 8 + jj]);
        }
        for (int w = tix; w < 65536; w += 8192) {
            const int en = w >> 14, ks2g = (w >> 9) & 31, hf2 = (w >> 8) & 1;
            const int el = (w >> 3) & 31, jj = w & 7;
            w2f[w] = __float2half(W2[(en * 32 + el) * 512 + ks2g * 16 + hf2 * 8 + jj]);
        }
    }
}

// ---------------- encoder (unchanged) ----------------
__global__ __launch_bounds__(256)
void enc_kernel(const float* __restrict__ x,
                const float* __restrict__ b1, const float* __restrict__ b2,
                const __half* __restrict__ w1f, const __half* __restrict__ w2f,
                __half* __restrict__ encH)
{
    __shared__ __align__(16) unsigned char smem[17408];
    float* x_s  = (float*)smem;
    __half* h_s = (__half*)smem;

    const int tid   = threadIdx.x;
    const int wv    = tid >> 6;
    const int lane  = tid & 63;
    const int l32   = lane & 31;
    const int half  = lane >> 5;
    const int msub  = wv >> 1;
    const int nhalf = wv & 1;
    const int m0    = blockIdx.x * 64;

    #pragma unroll
    for (int i = 0; i < 4; ++i) {
        const int f4 = i * 256 + tid;
        const int r = f4 >> 4, c4 = (f4 & 15) * 4;
        *(float4*)&x_s[r * 68 + c4] =
            *(const float4*)&x[(long long)(m0 + r) * 64 + c4];
    }
    __syncthreads();

    hfrag xa[4];
    #pragma unroll
    for (int ks = 0; ks < 4; ++ks) {
        const float* src = &x_s[(msub * 32 + l32) * 68 + ks * 16 + half * 8];
        const float4 a = *(const float4*)src;
        const float4 b = *(const float4*)(src + 4);
        hfrag v;
        v[0] = (_Float16)a.x; v[1] = (_Float16)a.y;
        v[2] = (_Float16)a.z; v[3] = (_Float16)a.w;
        v[4] = (_Float16)b.x; v[5] = (_Float16)b.y;
        v[6] = (_Float16)b.z; v[7] = (_Float16)b.w;
        xa[ks] = v;
    }
    __syncthreads();

    ffrag c2[2];
    c2[0] = 0.0f; c2[1] = 0.0f;

    for (int chunk = 0; chunk < 4; ++chunk) {
        ffrag c1[2];
        float b1j[2];
        #pragma unroll
        for (int nf = 0; nf < 2; ++nf) {
            const int jn = chunk * 4 + nhalf * 2 + nf;
            b1j[nf] = b1[jn * 32 + l32];
            ffrag acc = 0.0f;
            #pragma unroll
            for (int ks = 0; ks < 4; ++ks) {
                const hfrag bh = *(const hfrag*)(w1f + (jn * 4 + ks) * 512
                                                 + half * 256 + l32 * 8);
                acc = __builtin_amdgcn_mfma_f32_32x32x16_f16(xa[ks], bh, acc, 0, 0, 0);
            }
            c1[nf] = acc;
        }
        __syncthreads();
        #pragma unroll
        for (int nf = 0; nf < 2; ++nf) {
            #pragma unroll
            for (int i2 = 0; i2 < 16; ++i2) {
                const int m_row = (i2 & 3) + 8 * (i2 >> 2) + 4 * half;
                const float v = fmaxf(c1[nf][i2] + b1j[nf], 0.0f);
                h_s[(msub * 32 + m_row) * 136 + nhalf * 64 + nf * 32 + l32] =
                    __float2half(v);
            }
        }
        __syncthreads();
        #pragma unroll
        for (int ks2 = 0; ks2 < 8; ++ks2) {
            const hfrag a = *(const hfrag*)&h_s[(msub * 32 + l32) * 136
                                                + ks2 * 16 + half * 8];
            const int ks2g = chunk * 8 + ks2;
            #pragma unroll
            for (int ef = 0; ef < 2; ++ef) {
                const int en = nhalf * 2 + ef;
                const hfrag b = *(const hfrag*)(w2f + (en * 32 + ks2g) * 512
                                                + half * 256 + l32 * 8);
                c2[ef] = __builtin_amdgcn_mfma_f32_32x32x16_f16(a, b, c2[ef], 0, 0, 0);
            }
        }
    }

    #pragma unroll
    for (int ef = 0; ef < 2; ++ef) {
        const int e = nhalf * 64 + ef * 32 + l32;
        const float b2e = b2[e];
        #pragma unroll
        for (int i2 = 0; i2 < 16; ++i2) {
            const int m_row = (i2 & 3) + 8 * (i2 >> 2) + 4 * half;
            const int m_g = m0 + msub * 32 + m_row;
            encH[(long long)m_g * 128 + e] =
                __float2half(fmaxf(c2[ef][i2] + b2e, 0.0f));
        }
    }
}

// ---------------- init: v0[p][b] (unchanged) ----------------
__global__ __launch_bounds__(256, 2)
void init_kernel(const __half* __restrict__ encH, const float* __restrict__ Hf,
                 float* __restrict__ vOut)
{
    __shared__ float enc_s[64 * 129];
    const int tid = threadIdx.x;
    const int b0 = blockIdx.x * 64;     // grid 128
    {
        const int b = tid >> 2, ec = (tid & 3) * 32;
        const __half* er = encH + ((size_t)(b0 + b) * 12 + 0) * 128 + ec;
        #pragma unroll
        for (int q = 0; q < 4; ++q) {
            uint4 u = *(const uint4*)(er + q * 8);
            const __half* hp = (const __half*)&u;
            #pragma unroll
            for (int j = 0; j < 8; ++j)
                enc_s[b * 129 + ec + q * 8 + j] = __half2float(hp[j]);
        }
    }
    __syncthreads();
    const int wv = tid >> 6, lane = tid & 63;
    const int b = b0 + lane;
    for (int pc = 0; pc < 16; pc += 4) {
        const int p = wv * 16 + pc;
        float a0 = 0, a1 = 0, a2 = 0, a3 = 0;
        for (int e = 0; e < 128; ++e) {
            const float ev = enc_s[lane * 129 + e];
            const float4 h = *(const float4*)&Hf[e * 64 + p];
            a0 += ev * h.x; a1 += ev * h.y; a2 += ev * h.z; a3 += ev * h.w;
        }
        vOut[(size_t)(p + 0) * B_ALL + b] = a0;
        vOut[(size_t)(p + 1) * B_ALL + b] = a1;
        vOut[(size_t)(p + 2) * B_ALL + b] = a2;
        vOut[(size_t)(p + 3) * B_ALL + b] = a3;
    }
}

// ---------------- split: partials -> FRAG-ORDERED bf16 hi/lo planes ----------------
// plane addr(b,p) = ((bgrp*8 + s*2 + half)*32 + l32)*8 + j
//   bgrp=b>>5, l32=b&31, s=p>>4, half=(p>>3)&1, j=p&7
// 1024 frag-units per block (4 bgrp x 8 rowfrag x 32 lanes) -> k<4. (R8 bug: k<8
// generated bg_l 4..7 => OOB vsum reads + cross-block write race.)
__global__ __launch_bounds__(256)
void split_kernel(const float* __restrict__ vIn, int nIn,
                  unsigned short* __restrict__ vHi,
                  unsigned short* __restrict__ vLo)
{
    __shared__ float vsum[64 * 132];
    const int tid = threadIdx.x;
    const int bb = blockIdx.x;         // grid 64, 128 b each
    const int b0 = bb * 128;
    #pragma unroll
    for (int k = 0; k < 8; ++k) {
        const int p  = (tid >> 5) + k * 8;
        const int bl = (tid & 31) * 4;
        float4 s4 = {0.f, 0.f, 0.f, 0.f};
        for (int g = 0; g < nIn; ++g) {
            const float4 u = *(const float4*)&vIn[(size_t)g * 524288
                                                  + (size_t)p * B_ALL + b0 + bl];
            s4.x += u.x; s4.y += u.y; s4.z += u.z; s4.w += u.w;
        }
        *(float4*)&vsum[p * 132 + bl] = s4;
    }
    __syncthreads();
    #pragma unroll
    for (int k = 0; k < 4; ++k) {
        const int u = tid + k * 256;           // 1024 frag-units per block
        const int bg_l = u >> 8;               // 0..3
        const int rowfrag = (u >> 5) & 7;      // s*2+half
        const int l32 = u & 31;
        const int p0 = (rowfrag >> 1) * 16 + (rowfrag & 1) * 8;
        const int bcol = bg_l * 32 + l32;
        unsigned short hi8[8], lo8[8];
        #pragma unroll
        for (int j = 0; j < 8; ++j) {
            const float f = vsum[(p0 + j) * 132 + bcol];
            const unsigned short h = bf16_rne(f);
            hi8[j] = h;
            lo8[j] = bf16_rne(f - bf16_f32(h));
        }
        const size_t a = ((size_t)(bb * 4 + bg_l) * 8 + rowfrag) * 256
                       + (size_t)l32 * 8;
        *(uint4*)(vHi + a) = *(const uint4*)hi8;
        *(uint4*)(vLo + a) = *(const uint4*)lo8;
    }
}

// ---------------- chain step: pinned B-frags, frag-plane fed ----------------
__global__ __launch_bounds__(256, 2)
void chain_step(const unsigned short* __restrict__ Hth,  // this t hi [128e][4096]
                const unsigned short* __restrict__ Htl,
                const __half* __restrict__ encH,
                const unsigned short* __restrict__ vHiF,  // frag-ordered planes
                const unsigned short* __restrict__ vLoF,
                float* __restrict__ pOut,                 // [8][64][8192]
                int t)
{
    __shared__ float enc_s[16 * 132];
    const int tid = threadIdx.x;
    const int m = blockIdx.x & 63;     // 64 btiles (128 b)
    const int g = blockIdx.x >> 6;     // 8 e-groups
    const int b0 = m * 128;
    const int e0 = g * 16;

    // stage enc [16 e][128 b]
    if (tid < 128) {
        const __half* er = encH + ((size_t)((b0 + tid) * 12 + t)) * 128 + e0;
        uint4 u0 = *(const uint4*)er;
        uint4 u1 = *(const uint4*)(er + 8);
        const __half* h0 = (const __half*)&u0;
        const __half* h1 = (const __half*)&u1;
        #pragma unroll
        for (int el = 0; el < 8; ++el) enc_s[el * 132 + tid] = __half2float(h0[el]);
        #pragma unroll
        for (int el = 0; el < 8; ++el) enc_s[(el + 8) * 132 + tid] = __half2float(h1[el]);
    }

    const int wv = tid >> 6, lane = tid & 63;
    const int l32 = lane & 31, half = lane >> 5;
    const int mf = wv >> 1, bh = wv & 1;

    // B-frags: coalesced dwordx4 from frag planes, pinned in VGPRs
    bfrag vbh_[2][4], vbl_[2][4];
    #pragma unroll
    for (int nf = 0; nf < 2; ++nf) {
        const int bgrp = m * 4 + bh * 2 + nf;
        #pragma unroll
        for (int s = 0; s < 4; ++s) {
            const size_t base = ((size_t)(bgrp * 8 + s * 2 + half) * 32 + l32) * 8;
            v4i th = *(const v4i*)(vHiF + base);
            v4i tl = *(const v4i*)(vLoF + base);
            asm volatile("" : "+v"(th));
            asm volatile("" : "+v"(tl));
            vbh_[nf][s] = __builtin_bit_cast(bfrag, th);
            vbl_[nf][s] = __builtin_bit_cast(bfrag, tl);
        }
    }
    __syncthreads();

    ffrag z = 0.0f;
    ffrag vn0 = 0.0f, vn1 = 0.0f;

    #pragma unroll 4
    for (int e = 0; e < 16; ++e) {
        const float ev0 = enc_s[e * 132 + bh * 64 + l32];
        const float ev1 = enc_s[e * 132 + bh * 64 + 32 + l32];
        const unsigned short* hb = Hth + (size_t)(e0 + e) * 4096;
        const unsigned short* lb = Htl + (size_t)(e0 + e) * 4096;
        ffrag wa = z, wb = z;
        #pragma unroll
        for (int s = 0; s < 4; ++s) {
            const int fo = (((mf * 4 + s) * 2 + half) * 32 + l32) * 8;
            const bfrag ah = *(const bfrag*)(hb + fo);
            const bfrag al = *(const bfrag*)(lb + fo);
            wa = __builtin_amdgcn_mfma_f32_32x32x16_bf16(ah, vbh_[0][s], wa, 0, 0, 0);
            wa = __builtin_amdgcn_mfma_f32_32x32x16_bf16(ah, vbl_[0][s], wa, 0, 0, 0);
            wa = __builtin_amdgcn_mfma_f32_32x32x16_bf16(al, vbh_[0][s], wa, 0, 0, 0);
            wb = __builtin_amdgcn_mfma_f32_32x32x16_bf16(ah, vbh_[1][s], wb, 0, 0, 0);
            wb = __builtin_amdgcn_mfma_f32_32x32x16_bf16(ah, vbl_[1][s], wb, 0, 0, 0);
            wb = __builtin_amdgcn_mfma_f32_32x32x16_bf16(al, vbh_[1][s], wb, 0, 0, 0);
        }
        vn0 += wa * ev0;
        vn1 += wb * ev1;
    }

    #pragma unroll
    for (int nf = 0; nf < 2; ++nf) {
        const ffrag vv = nf ? vn1 : vn0;
        const int b = b0 + bh * 64 + nf * 32 + l32;
        #pragma unroll
        for (int i = 0; i < 16; ++i) {
            const int r = mf * 32 + (i & 3) + 8 * (i >> 2) + 4 * half;
            pOut[(size_t)g * 524288 + (size_t)r * B_ALL + b] = vv[i];
        }
    }
}

// ---------------- reduce + transpose (unchanged) ----------------
__global__ __launch_bounds__(256)
void reduce_t_kernel(const float* __restrict__ vIn, int nIn,
                     float* __restrict__ vT)
{
    __shared__ float vt[64][68];
    const int tid = threadIdx.x;
    const int b0 = blockIdx.x * 64;   // grid 128
    #pragma unroll
    for (int k = 0; k < 8; ++k) {
        const int p  = (tid >> 5) + k * 8;
        const int bl = (tid & 31) * 2;
        float2 s = {0.f, 0.f};
        for (int g = 0; g < nIn; ++g) {
            const float2 u = *(const float2*)&vIn[(size_t)g * 524288
                                                  + (size_t)p * B_ALL + b0 + bl];
            s.x += u.x; s.y += u.y;
        }
        vt[bl][p] = s.x;
        vt[bl + 1][p] = s.y;
    }
    __syncthreads();
    const int b = tid >> 2, c = (tid & 3) * 16;
    float4* dst = (float4*)&vT[(size_t)(b0 + b) * 64 + c];
    #pragma unroll
    for (int q = 0; q < 4; ++q)
        dst[q] = *(float4*)&vt[b][c + q * 4];
}

// ---------------- final (unchanged) ----------------
__global__ __launch_bounds__(64)
void final_kernel(const __half* __restrict__ encH, const float* __restrict__ HL,
                  const float* __restrict__ vT, float* __restrict__ out)
{
    __shared__ float hl_s[64 * 129];
    const int tid = threadIdx.x;
    const int b0 = blockIdx.x * 16;
    for (int i = 0; i < 128; ++i) {
        const int idx = i * 64 + tid;
        hl_s[(idx >> 7) * 129 + (idx & 127)] = HL[idx];
    }
    __syncthreads();
    const int p = tid;
    for (int bs = 0; bs < 16; ++bs) {
        const int b = b0 + bs;
        const __half* er = encH + (size_t)(b * 12 + 11) * 128;
        float L = 0.0f;
        #pragma unroll 16
        for (int e = 0; e < 128; ++e)
            L += __half2float(er[e]) * hl_s[p * 129 + e];
        float pre = vT[(size_t)b * 64 + p] * L;
        #pragma unroll
        for (int off = 32; off > 0; off >>= 1)
            pre += __shfl_down(pre, off);
        if (tid == 0) out[b] = pre;
    }
}

extern "C" void kernel_launch(void* const* d_in, const int* in_sizes, int n_in,
                              void* d_out, int out_size, void* d_ws, size_t ws_size,
                              hipStream_t stream) {
    const float* x  = (const float*)d_in[0];
    const float* W1 = (const float*)d_in[1];
    const float* b1 = (const float*)d_in[2];
    const float* W2 = (const float*)d_in[3];
    const float* b2 = (const float*)d_in[4];
    const float* Hf = (const float*)d_in[5];
    const float* Hm = (const float*)d_in[6];
    const float* HL = (const float*)d_in[7];
    float* out = (float*)d_out;
    (void)in_sizes; (void)n_in; (void)out_size; (void)ws_size;

    char* ws = (char*)d_ws;
    __half* encH        = (__half*)(ws + O_ENC);
    unsigned short* HmH = (unsigned short*)(ws + O_HMH);
    unsigned short* HmL = (unsigned short*)(ws + O_HML);
    __half* w1f         = (__half*)(ws + O_W1F);
    __half* w2f         = (__half*)(ws + O_W2F);
    float* v0           = (float*)(ws + O_V0);
    float* vT           = (float*)(ws + O_V0);
    unsigned short* vHi = (unsigned short*)(ws + O_VHI);
    unsigned short* vLo = (unsigned short*)(ws + O_VLO);
    float* pA           = (float*)(ws + O_PA);

    prep_kernel<<<dim3(2592), dim3(256), 0, stream>>>(W1, W2, Hm, w1f, w2f, HmH, HmL);
    enc_kernel<<<dim3(1536), dim3(256), 0, stream>>>(x, b1, b2, w1f, w2f, encH);
    init_kernel<<<dim3(128), dim3(256), 0, stream>>>(encH, Hf, v0);
    split_kernel<<<dim3(64), dim3(256), 0, stream>>>(v0, 1, vHi, vLo);

    for (int t = 1; t <= 10; ++t) {
        chain_step<<<dim3(512), dim3(256), 0, stream>>>(
            HmH + (size_t)(t - 1) * 524288, HmL + (size_t)(t - 1) * 524288,
            encH, vHi, vLo, pA, t);
        if (t < 10)
            split_kernel<<<dim3(64), dim3(256), 0, stream>>>(pA, 8, vHi, vLo);
    }
    reduce_t_kernel<<<dim3(128), dim3(256), 0, stream>>>(pA, 8, vT);
    final_kernel<<<dim3(512), dim3(64), 0, stream>>>(encH, HL, vT, out);
}